// Round 4
// baseline (298.113 us; speedup 1.0000x reference)
//
#include <hip/hip_runtime.h>
#include <math.h>

// src [B=16,S=4096,DM=768] fp32, mask [B,S] bool, query [H=8,D=96] fp32,
// out [B,768] fp32.
//   w_s = exp(q.k_s)  (scores ~ N(0,1): no max-subtraction needed in fp32)
//   out = (sum_s w_s k_s + sum_s w_s pe_s) / sum_s w_s
// Pass 1: one block per (b, s-chunk), ALL heads together -> fully contiguous
//   streaming. Lane i owns channels [12i,12i+12): head = lane>>3, so head
//   segments align with 8-lane groups (score reduce = 3 shfl_xor width 8).
// Pass 2: sum_s w_s*pe[s,c] via sin/cos rotation recurrence over L2-hot w.
// Pass 3: merge chunk partials and divide.
namespace {
constexpr int kB = 16;
constexpr int kS = 4096;
constexpr int kH = 8;
constexpr int kD = 96;
constexpr int kDM = 768;
constexpr int kNC = 64;                 // s-chunks per batch -> 16*64 = 1024 blocks
constexpr int kCS = kS / kNC;           // 64 rows per chunk
constexpr int kRW = kCS / 4;            // 16 rows per wave (4 waves/block)
constexpr int kNSC2 = 32;               // pass-2 s-chunks
constexpr int kS2 = kS / kNSC2;         // 128
constexpr float kPeScale = 0.03608439182435161f;        // 768^-0.5
constexpr float kNegLog = -9.210340371976184f / 768.0f; // -ln(1e4)/768
constexpr float kHalfPi = 1.5707963267948966f;
}

__global__ __launch_bounds__(256)
void attn_pass1(const float* __restrict__ src,
                const unsigned char* __restrict__ mask,
                const float* __restrict__ query,
                float* __restrict__ wsO,
                float* __restrict__ wsL,
                float* __restrict__ wsW)
{
    const int blk = (int)blockIdx.x;
    const int b = blk >> 6;             // / kNC
    const int chunk = blk & (kNC - 1);
    const int t = (int)threadIdx.x;
    const int wave = t >> 6;
    const int lane = t & 63;
    const int h = lane >> 3;            // head owning this lane's channels

    // query flat [768]: channel c = h*96+d, identical indexing to src row.
    const float* qf = query + 12 * lane;
    const float4 q0 = *(const float4*)(qf);
    const float4 q1 = *(const float4*)(qf + 4);
    const float4 q2 = *(const float4*)(qf + 8);

    float l = 0.0f;
    float o[12];
#pragma unroll
    for (int k = 0; k < 12; ++k) o[k] = 0.0f;

    // wave handles rows s = chunk*64 + wave + 4*it
    const int s0 = chunk * kCS + wave;
    const float* base = src + ((size_t)b * kS + s0) * kDM + 12 * lane;
    const unsigned char* mb = mask + (size_t)b * kS + s0;
    float* wb = wsW + ((size_t)b * kS + s0) * kH + h;

    float4 x0 = *(const float4*)(base);
    float4 x1 = *(const float4*)(base + 4);
    float4 x2 = *(const float4*)(base + 8);
    unsigned char mk = mb[0];

    for (int it = 0; it < kRW; ++it) {
        float4 nx0 = {}, nx1 = {}, nx2 = {};
        unsigned char nmk = 0;
        if (it + 1 < kRW) {
            const float* np = base + (size_t)((it + 1) * 4) * kDM;
            nx0 = *(const float4*)(np);
            nx1 = *(const float4*)(np + 4);
            nx2 = *(const float4*)(np + 8);
            nmk = mb[(it + 1) * 4];
        }

        float pd = x0.x * q0.x + x0.y * q0.y + x0.z * q0.z + x0.w * q0.w
                 + x1.x * q1.x + x1.y * q1.y + x1.z * q1.z + x1.w * q1.w
                 + x2.x * q2.x + x2.y * q2.y + x2.z * q2.z + x2.w * q2.w;
        pd += __shfl_xor(pd, 1, 8);
        pd += __shfl_xor(pd, 2, 8);
        pd += __shfl_xor(pd, 4, 8);     // all 8 lanes of the head group share pd

        const float w = mk ? 0.0f : __expf(pd);
        l += w;

        o[0]  = fmaf(w, x0.x, o[0]);
        o[1]  = fmaf(w, x0.y, o[1]);
        o[2]  = fmaf(w, x0.z, o[2]);
        o[3]  = fmaf(w, x0.w, o[3]);
        o[4]  = fmaf(w, x1.x, o[4]);
        o[5]  = fmaf(w, x1.y, o[5]);
        o[6]  = fmaf(w, x1.z, o[6]);
        o[7]  = fmaf(w, x1.w, o[7]);
        o[8]  = fmaf(w, x2.x, o[8]);
        o[9]  = fmaf(w, x2.y, o[9]);
        o[10] = fmaf(w, x2.z, o[10]);
        o[11] = fmaf(w, x2.w, o[11]);

        // w store: lanes 0,8,..,56 -> 8 consecutive floats (32 B contiguous)
        if ((lane & 7) == 0) wb[(size_t)(it * 4) * kH] = w;

        x0 = nx0; x1 = nx1; x2 = nx2; mk = nmk;
    }

    // ---- block reduction across the 4 waves ----
    __shared__ float osum[4][kDM];      // 12 KB
    __shared__ float lsum[4][kH];

    float* op = &osum[wave][12 * lane];
    ((float4*)op)[0] = make_float4(o[0], o[1], o[2], o[3]);
    ((float4*)op)[1] = make_float4(o[4], o[5], o[6], o[7]);
    ((float4*)op)[2] = make_float4(o[8], o[9], o[10], o[11]);
    if ((lane & 7) == 0) lsum[wave][h] = l;
    __syncthreads();

    if (t < kDM / 4) {
        const float4 a0 = ((const float4*)&osum[0][0])[t];
        const float4 a1 = ((const float4*)&osum[1][0])[t];
        const float4 a2 = ((const float4*)&osum[2][0])[t];
        const float4 a3 = ((const float4*)&osum[3][0])[t];
        float4 r;
        r.x = a0.x + a1.x + a2.x + a3.x;
        r.y = a0.y + a1.y + a2.y + a3.y;
        r.z = a0.z + a1.z + a2.z + a3.z;
        r.w = a0.w + a1.w + a2.w + a3.w;
        ((float4*)(wsO + (size_t)blk * kDM))[t] = r;
    }
    if (t < kH) {
        wsL[blk * kH + t] = lsum[0][t] + lsum[1][t] + lsum[2][t] + lsum[3][t];
    }
}

// Pass 2: wsP[(bh*32+sc)*96 + c] = kPeScale * sum_{s in chunk} w[b][s][h] *
//   sin(s*f_c + (c odd ? pi/2 : 0)),  f_c = exp(-ln(1e4)*(h*96 + (c&~1))/768).
// All lanes of a block read the same w address per step -> L1 broadcast.
__global__ __launch_bounds__(128)
void attn_pe(const float* __restrict__ wsW, float* __restrict__ wsP)
{
    const int blk = (int)blockIdx.x;    // bh*kNSC2 + sc
    const int sc = blk & (kNSC2 - 1);
    const int bh = blk >> 5;
    const int b = bh >> 3;
    const int h = bh & 7;
    const int c = (int)threadIdx.x;
    if (c >= kD) return;

    const float f = __expf(kNegLog * (float)(h * kD + (c & ~1)));
    const int s0 = sc * kS2;
    float sn, cs;
    __sincosf((float)s0 * f + ((c & 1) ? kHalfPi : 0.0f), &sn, &cs);
    float ds, dc;
    __sincosf(f, &ds, &dc);

    const float* wp = wsW + ((size_t)b * kS + s0) * kH + h;
    float acc = 0.0f;
#pragma unroll 4
    for (int i = 0; i < kS2; ++i) {
        const float w = wp[(size_t)i * kH];
        acc = fmaf(w, sn, acc);
        const float ns = fmaf(sn, dc, cs * ds);
        const float nc = fmaf(cs, dc, -sn * ds);
        sn = ns; cs = nc;
    }
    wsP[(size_t)blk * kD + c] = acc * kPeScale;
}

// Pass 3: out[bh*96+d] = (sum_cc O + sum_sc P) / sum_cc L.
__global__ __launch_bounds__(128)
void attn_combine(const float* __restrict__ wsO,
                  const float* __restrict__ wsL,
                  const float* __restrict__ wsP,
                  float* __restrict__ out)
{
    const int bh = (int)blockIdx.x;
    const int b = bh >> 3;
    const int h = bh & 7;
    const int t = (int)threadIdx.x;

    float L = 0.0f;
#pragma unroll
    for (int cc = 0; cc < kNC; ++cc) L += wsL[(b * kNC + cc) * kH + h];

    if (t < kD) {
        float acc = 0.0f;
#pragma unroll 8
        for (int cc = 0; cc < kNC; ++cc)
            acc += wsO[(size_t)(b * kNC + cc) * kDM + h * kD + t];
#pragma unroll 8
        for (int sc = 0; sc < kNSC2; ++sc)
            acc += wsP[(size_t)(bh * kNSC2 + sc) * kD + t];
        out[(size_t)bh * kD + t] = acc / L;
    }
}

extern "C" void kernel_launch(void* const* d_in, const int* in_sizes, int n_in,
                              void* d_out, int out_size, void* d_ws, size_t ws_size,
                              hipStream_t stream)
{
    const float* src = (const float*)d_in[0];
    const unsigned char* mask = (const unsigned char*)d_in[1];
    const float* query = (const float*)d_in[2];
    float* out = (float*)d_out;

    float* wsO = (float*)d_ws;                              // [1024, 768]
    float* wsL = wsO + (size_t)kB * kNC * kDM;              // [1024, 8]
    float* wsW = wsL + (size_t)kB * kNC * kH;               // [16, 4096, 8]
    float* wsP = wsW + (size_t)kB * kS * kH;                // [128*32, 96]

    hipLaunchKernelGGL(attn_pass1,
                       dim3(kB * kNC), dim3(256), 0, stream,
                       src, mask, query, wsO, wsL, wsW);
    hipLaunchKernelGGL(attn_pe,
                       dim3(kB * kH * kNSC2), dim3(128), 0, stream,
                       wsW, wsP);
    hipLaunchKernelGGL(attn_combine,
                       dim3(kB * kH), dim3(128), 0, stream,
                       wsO, wsL, wsP, out);
}

// Round 5
// 280.353 us; speedup vs baseline: 1.0634x; 1.0634x over previous
//
#include <hip/hip_runtime.h>
#include <math.h>

// src [B=16,S=4096,DM=768] fp32, mask [B,S] bool, query [H=8,D=96] fp32,
// out [B,768] fp32.
//   w_s = exp(q.k_s)   (scores ~ N(0,1): no max-subtraction needed in fp32)
//   out[b,h,:] = sum_s w_s (k_s + pe_s) / sum_s w_s
// Single streaming pass: one block per (b, s-chunk of 64 rows); all 8 heads
// handled together so each block reads fully contiguous memory. Lane i owns
// channels [12i, 12i+12); head = lane>>3 aligns head segments with 8-lane
// groups (score reduce = 3 shfl_xor width 8). PE is generated inline with a
// sin/cos rotation recurrence (no per-row transcendentals, no second pass).
// A tiny combine kernel merges the 64 chunk-partials per batch.
namespace {
constexpr int kB = 16;
constexpr int kS = 4096;
constexpr int kH = 8;
constexpr int kD = 96;
constexpr int kDM = 768;
constexpr int kNC = 64;                 // s-chunks per batch -> 16*64 = 1024 blocks
constexpr int kCS = kS / kNC;           // 64 rows per chunk
constexpr int kRW = kCS / 4;            // 16 rows per wave (4 waves/block)
constexpr float kPeScale = 0.03608439182435161f;        // 768^-0.5
constexpr float kNegLog = -9.210340371976184f / 768.0f; // -ln(1e4)/768
}

__global__ __launch_bounds__(256)
void attn_pass1(const float* __restrict__ src,
                const unsigned char* __restrict__ mask,
                const float* __restrict__ query,
                float* __restrict__ wsO,
                float* __restrict__ wsL)
{
    const int blk = (int)blockIdx.x;
    const int b = blk >> 6;             // / kNC
    const int chunk = blk & (kNC - 1);
    const int t = (int)threadIdx.x;
    const int wave = t >> 6;
    const int lane = t & 63;
    const int h = lane >> 3;            // head owning this lane's channels

    // query flat [768]: channel c = h*96+d — same indexing as a src row.
    const float* qf = query + 12 * lane;
    const float4 q0 = *(const float4*)(qf);
    const float4 q1 = *(const float4*)(qf + 4);
    const float4 q2 = *(const float4*)(qf + 8);

    // 6 (sin,cos) channel pairs for this lane: even channels cb+0,2,..,10.
    const int cb = 12 * lane;
    float f[6], sn[6], cs[6], dsn[6], dcs[6];
#pragma unroll
    for (int p = 0; p < 6; ++p)
        f[p] = __expf(kNegLog * (float)(cb + 2 * p));

    // wave handles rows s = chunk*64 + wave + 4*it
    const int s0 = chunk * kCS + wave;
#pragma unroll
    for (int p = 0; p < 6; ++p) {
        __sincosf((float)s0 * f[p], &sn[p], &cs[p]);
        __sincosf(4.0f * f[p], &dsn[p], &dcs[p]);
    }

    float l = 0.0f;
    float o[12];
#pragma unroll
    for (int k = 0; k < 12; ++k) o[k] = 0.0f;

    const float* base = src + ((size_t)b * kS + s0) * kDM + 12 * lane;
    const unsigned char* mb = mask + (size_t)b * kS + s0;

    float4 x0 = *(const float4*)(base);
    float4 x1 = *(const float4*)(base + 4);
    float4 x2 = *(const float4*)(base + 8);
    unsigned char mk = mb[0];

    for (int it = 0; it < kRW; ++it) {
        float4 nx0 = {}, nx1 = {}, nx2 = {};
        unsigned char nmk = 0;
        if (it + 1 < kRW) {
            const float* np = base + (size_t)((it + 1) * 4) * kDM;
            nx0 = *(const float4*)(np);
            nx1 = *(const float4*)(np + 4);
            nx2 = *(const float4*)(np + 8);
            nmk = mb[(it + 1) * 4];
        }

        float pd = x0.x * q0.x + x0.y * q0.y + x0.z * q0.z + x0.w * q0.w
                 + x1.x * q1.x + x1.y * q1.y + x1.z * q1.z + x1.w * q1.w
                 + x2.x * q2.x + x2.y * q2.y + x2.z * q2.z + x2.w * q2.w;
        pd += __shfl_xor(pd, 1, 8);
        pd += __shfl_xor(pd, 2, 8);
        pd += __shfl_xor(pd, 4, 8);     // 8 lanes of the head group share pd

        const float w = mk ? 0.0f : __expf(pd);
        l += w;

        // o[c] += w * (x[c] + pe[c]);  even c -> sin, odd c -> cos
        o[0]  = fmaf(w, fmaf(sn[0], kPeScale, x0.x), o[0]);
        o[1]  = fmaf(w, fmaf(cs[0], kPeScale, x0.y), o[1]);
        o[2]  = fmaf(w, fmaf(sn[1], kPeScale, x0.z), o[2]);
        o[3]  = fmaf(w, fmaf(cs[1], kPeScale, x0.w), o[3]);
        o[4]  = fmaf(w, fmaf(sn[2], kPeScale, x1.x), o[4]);
        o[5]  = fmaf(w, fmaf(cs[2], kPeScale, x1.y), o[5]);
        o[6]  = fmaf(w, fmaf(sn[3], kPeScale, x1.z), o[6]);
        o[7]  = fmaf(w, fmaf(cs[3], kPeScale, x1.w), o[7]);
        o[8]  = fmaf(w, fmaf(sn[4], kPeScale, x2.x), o[8]);
        o[9]  = fmaf(w, fmaf(cs[4], kPeScale, x2.y), o[9]);
        o[10] = fmaf(w, fmaf(sn[5], kPeScale, x2.z), o[10]);
        o[11] = fmaf(w, fmaf(cs[5], kPeScale, x2.w), o[11]);

        // rotate phases forward by 4 rows
#pragma unroll
        for (int p = 0; p < 6; ++p) {
            const float ns = fmaf(sn[p], dcs[p], cs[p] * dsn[p]);
            const float nc = fmaf(cs[p], dcs[p], -sn[p] * dsn[p]);
            sn[p] = ns; cs[p] = nc;
        }

        x0 = nx0; x1 = nx1; x2 = nx2; mk = nmk;
    }

    // ---- block reduction across the 4 waves ----
    __shared__ float osum[4][kDM];      // 12 KB
    __shared__ float lsum[4][kH];

    float* op = &osum[wave][12 * lane];
    ((float4*)op)[0] = make_float4(o[0], o[1], o[2], o[3]);
    ((float4*)op)[1] = make_float4(o[4], o[5], o[6], o[7]);
    ((float4*)op)[2] = make_float4(o[8], o[9], o[10], o[11]);
    if ((lane & 7) == 0) lsum[wave][h] = l;
    __syncthreads();

    if (t < kDM / 4) {
        const float4 a0 = ((const float4*)&osum[0][0])[t];
        const float4 a1 = ((const float4*)&osum[1][0])[t];
        const float4 a2 = ((const float4*)&osum[2][0])[t];
        const float4 a3 = ((const float4*)&osum[3][0])[t];
        float4 r;
        r.x = a0.x + a1.x + a2.x + a3.x;
        r.y = a0.y + a1.y + a2.y + a3.y;
        r.z = a0.z + a1.z + a2.z + a3.z;
        r.w = a0.w + a1.w + a2.w + a3.w;
        ((float4*)(wsO + (size_t)blk * kDM))[t] = r;
    }
    if (t < kH) {
        wsL[blk * kH + t] = lsum[0][t] + lsum[1][t] + lsum[2][t] + lsum[3][t];
    }
}

// Combine: one block per batch, 768 threads. Thread d sums the 64 chunk
// partials (fully coalesced: consecutive threads -> consecutive addresses)
// and divides by the head's weight sum.
__global__ __launch_bounds__(768)
void attn_combine(const float* __restrict__ wsO,
                  const float* __restrict__ wsL,
                  float* __restrict__ out)
{
    const int b = (int)blockIdx.x;
    const int d = (int)threadIdx.x;

    __shared__ float Ls[kH];
    if (d < kH) {
        float L = 0.0f;
#pragma unroll
        for (int cc = 0; cc < kNC; ++cc) L += wsL[(b * kNC + cc) * kH + d];
        Ls[d] = L;
    }
    __syncthreads();

    float acc = 0.0f;
#pragma unroll 8
    for (int cc = 0; cc < kNC; ++cc)
        acc += wsO[(size_t)(b * kNC + cc) * kDM + d];
    out[(size_t)b * kDM + d] = acc / Ls[d / kD];
}

extern "C" void kernel_launch(void* const* d_in, const int* in_sizes, int n_in,
                              void* d_out, int out_size, void* d_ws, size_t ws_size,
                              hipStream_t stream)
{
    const float* src = (const float*)d_in[0];
    const unsigned char* mask = (const unsigned char*)d_in[1];
    const float* query = (const float*)d_in[2];
    float* out = (float*)d_out;

    float* wsO = (float*)d_ws;                              // [1024, 768]
    float* wsL = wsO + (size_t)kB * kNC * kDM;              // [1024, 8]

    hipLaunchKernelGGL(attn_pass1,
                       dim3(kB * kNC), dim3(256), 0, stream,
                       src, mask, query, wsO, wsL);
    hipLaunchKernelGGL(attn_combine,
                       dim3(kB), dim3(kDM), 0, stream,
                       wsO, wsL, out);
}